// Round 1
// baseline (271.559 us; speedup 1.0000x reference)
//
#include <hip/hip_runtime.h>
#include <hip/hip_bf16.h>
#include <math.h>

#define FEAT 1024
#define HID  512
#define DK   256
#define NROWS 8192

#define TM 128
#define TN 128
#define BK 16

// ---------------------------------------------------------------------------
// Tiled fp32 GEMM: C = [relu](A @ B + bias). blockIdx.z selects among up to 3
// (B, bias, C) triples so independent GEMMs sharing A fill the GPU in one
// launch. 256 threads, 128x128 tile, 8x8 per-thread micro-tile, BK=16.
// ---------------------------------------------------------------------------
__global__ __launch_bounds__(256) void gemm3_f32(
    const float* __restrict__ A,
    const float* __restrict__ B0, const float* __restrict__ B1, const float* __restrict__ B2,
    const float* __restrict__ bias0, const float* __restrict__ bias1, const float* __restrict__ bias2,
    float* __restrict__ C0, float* __restrict__ C1, float* __restrict__ C2,
    int M, int N, int K, int do_relu)
{
    const float* B    = (blockIdx.z == 0) ? B0    : (blockIdx.z == 1) ? B1    : B2;
    const float* bias = (blockIdx.z == 0) ? bias0 : (blockIdx.z == 1) ? bias1 : bias2;
    float*       C    = (blockIdx.z == 0) ? C0    : (blockIdx.z == 1) ? C1    : C2;

    __shared__ float As[BK][TM];  // transposed A tile: As[k][m]
    __shared__ float Bs[BK][TN];  // Bs[k][n]

    const int tid = threadIdx.x;
    const int tx = tid & 15;       // 0..15 -> output column group
    const int ty = tid >> 4;       // 0..15 -> output row group
    const int m0 = blockIdx.y * TM;
    const int n0 = blockIdx.x * TN;

    float acc[8][8];
    #pragma unroll
    for (int i = 0; i < 8; ++i)
        #pragma unroll
        for (int j = 0; j < 8; ++j) acc[i][j] = 0.f;

    for (int kt = 0; kt < K; kt += BK) {
        // Load A tile (128 rows x 16 k), store transposed to LDS.
        #pragma unroll
        for (int l = 0; l < 2; ++l) {
            int idx = tid + l * 256;           // 0..511
            int row = idx >> 2;                // 0..127
            int seg = idx & 3;                 // 4 float4 per row
            float4 a = *(const float4*)(A + (size_t)(m0 + row) * K + kt + seg * 4);
            As[seg * 4 + 0][row] = a.x;
            As[seg * 4 + 1][row] = a.y;
            As[seg * 4 + 2][row] = a.z;
            As[seg * 4 + 3][row] = a.w;
        }
        // Load B tile (16 k x 128 n), same layout as global -> float4 direct.
        #pragma unroll
        for (int l = 0; l < 2; ++l) {
            int idx = tid + l * 256;
            int row = idx >> 5;                // 0..15
            int c4  = idx & 31;                // 32 float4 per row
            *(float4*)(&Bs[row][c4 * 4]) =
                *(const float4*)(B + (size_t)(kt + row) * N + n0 + c4 * 4);
        }
        __syncthreads();

        #pragma unroll
        for (int k = 0; k < BK; ++k) {
            float a[8], b[8];
            #pragma unroll
            for (int j = 0; j < 8; ++j) a[j] = As[k][ty * 8 + j];
            #pragma unroll
            for (int j = 0; j < 8; ++j) b[j] = Bs[k][tx * 8 + j];
            #pragma unroll
            for (int i = 0; i < 8; ++i)
                #pragma unroll
                for (int j = 0; j < 8; ++j)
                    acc[i][j] = fmaf(a[i], b[j], acc[i][j]);
        }
        __syncthreads();
    }

    // Epilogue: bias + optional relu, float4 stores.
    #pragma unroll
    for (int i = 0; i < 8; ++i) {
        int m = m0 + ty * 8 + i;
        #pragma unroll
        for (int j4 = 0; j4 < 2; ++j4) {
            int n = n0 + tx * 8 + j4 * 4;
            float4 v;
            v.x = acc[i][j4 * 4 + 0];
            v.y = acc[i][j4 * 4 + 1];
            v.z = acc[i][j4 * 4 + 2];
            v.w = acc[i][j4 * 4 + 3];
            if (bias) {
                v.x += bias[n + 0]; v.y += bias[n + 1];
                v.z += bias[n + 2]; v.w += bias[n + 3];
            }
            if (do_relu) {
                v.x = fmaxf(v.x, 0.f); v.y = fmaxf(v.y, 0.f);
                v.z = fmaxf(v.z, 0.f); v.w = fmaxf(v.w, 0.f);
            }
            *(float4*)(C + (size_t)m * N + n) = v;
        }
    }
}

// ---------------------------------------------------------------------------
// One wave per row i: gather 9 K-rows per sp_matrix, incremental prefix sums,
// a_raw[sel][i] = q_i . ksum / 16 at prefix lengths {3,5,9}.
// ---------------------------------------------------------------------------
__global__ __launch_bounds__(64) void gather_attn(
    const float* __restrict__ Q, const float* __restrict__ Kmat,
    const int* __restrict__ sp, float* __restrict__ a_raw)
{
    const int i = blockIdx.x;
    const int lane = threadIdx.x;

    float4 q = *(const float4*)(Q + (size_t)i * DK + lane * 4);
    float4 ks = make_float4(0.f, 0.f, 0.f, 0.f);

    int sel = 0;
    #pragma unroll
    for (int j = 0; j <= 8; ++j) {
        int r = sp[i * 9 + j];
        float4 kv = *(const float4*)(Kmat + (size_t)r * DK + lane * 4);
        ks.x += kv.x; ks.y += kv.y; ks.z += kv.z; ks.w += kv.w;
        if (j == 2 || j == 4 || j == 8) {
            float d = q.x * ks.x + q.y * ks.y + q.z * ks.z + q.w * ks.w;
            #pragma unroll
            for (int off = 32; off; off >>= 1) d += __shfl_xor(d, off);
            if (lane == 0) a_raw[sel * NROWS + i] = d * 0.0625f;  // /sqrt(256)
            ++sel;
        }
    }
}

// ---------------------------------------------------------------------------
// Max over N per selector (3 blocks).
// ---------------------------------------------------------------------------
__global__ __launch_bounds__(1024) void reduce_max_k(
    const float* __restrict__ a_raw, float* __restrict__ mx)
{
    __shared__ float s[1024];
    const int sel = blockIdx.x;
    float m = -INFINITY;
    for (int i = threadIdx.x; i < NROWS; i += 1024)
        m = fmaxf(m, a_raw[sel * NROWS + i]);
    s[threadIdx.x] = m;
    __syncthreads();
    for (int st = 512; st; st >>= 1) {
        if (threadIdx.x < st) s[threadIdx.x] = fmaxf(s[threadIdx.x], s[threadIdx.x + st]);
        __syncthreads();
    }
    if (threadIdx.x == 0) mx[sel] = s[0];
}

// ---------------------------------------------------------------------------
// Weighted pools: P[sel][d] = sum_i e_i V[i][d], Z[sel] = sum_i e_i,
// e_i = exp(a_raw[sel][i] - mx[sel]). Block handles 128 rows; thread = column.
// ---------------------------------------------------------------------------
#define RPB 128
__global__ __launch_bounds__(256) void pool_kernel(
    const float* __restrict__ a_raw, const float* __restrict__ mx,
    const float* __restrict__ V, float* __restrict__ P, float* __restrict__ Z)
{
    const int sel = blockIdx.y;
    const int r0 = blockIdx.x * RPB;
    const int t = threadIdx.x;

    __shared__ float e[RPB];
    __shared__ float zs[4];

    const float m = mx[sel];
    float zp = 0.f;
    if (t < RPB) {
        float v = expf(a_raw[sel * NROWS + r0 + t] - m);
        e[t] = v;
        zp = v;
    }
    __syncthreads();

    float acc = 0.f;
    for (int r = 0; r < RPB; ++r)
        acc = fmaf(e[r], V[(size_t)(r0 + r) * DK + t], acc);
    atomicAdd(&P[sel * DK + t], acc);

    #pragma unroll
    for (int off = 32; off; off >>= 1) zp += __shfl_xor(zp, off);
    if ((t & 63) == 0) zs[t >> 6] = zp;
    __syncthreads();
    if (t == 0) atomicAdd(&Z[sel], zs[0] + zs[1] + zs[2] + zs[3]);
}

// ---------------------------------------------------------------------------
// Final: s = sum_sel P[sel]/Z[sel]; logits = s @ Wout + bout; softmax(2).
// ---------------------------------------------------------------------------
__global__ __launch_bounds__(256) void final_kernel(
    const float* __restrict__ P, const float* __restrict__ Z,
    const float* __restrict__ Wout, const float* __restrict__ bout,
    float* __restrict__ out)
{
    const int t = threadIdx.x;  // = d in 0..255
    float s = P[t] / Z[0] + P[DK + t] / Z[1] + P[2 * DK + t] / Z[2];
    __shared__ float s0[256], s1[256];
    s0[t] = s * Wout[t * 2 + 0];
    s1[t] = s * Wout[t * 2 + 1];
    __syncthreads();
    for (int st = 128; st; st >>= 1) {
        if (t < st) { s0[t] += s0[t + st]; s1[t] += s1[t + st]; }
        __syncthreads();
    }
    if (t == 0) {
        float a = s0[0] + bout[0], b = s1[0] + bout[1];
        float mm = fmaxf(a, b);
        float ea = expf(a - mm), eb = expf(b - mm);
        float inv = 1.f / (ea + eb);
        out[0] = ea * inv;
        out[1] = eb * inv;
    }
}

// ---------------------------------------------------------------------------
extern "C" void kernel_launch(void* const* d_in, const int* in_sizes, int n_in,
                              void* d_out, int out_size, void* d_ws, size_t ws_size,
                              hipStream_t stream)
{
    const float* X    = (const float*)d_in[0];   // 8192 x 1024
    const int*   sp   = (const int*)  d_in[1];   // 8192 x 9
    const float* W1   = (const float*)d_in[2];   // 1024 x 512
    const float* b1   = (const float*)d_in[3];   // 512
    const float* Wq   = (const float*)d_in[4];   // 512 x 256
    const float* Wk   = (const float*)d_in[5];
    const float* Wv   = (const float*)d_in[6];
    const float* bv   = (const float*)d_in[7];   // 256
    const float* Wout = (const float*)d_in[8];   // 256 x 2
    const float* bout = (const float*)d_in[9];   // 2
    float* out = (float*)d_out;

    // Workspace layout (floats)
    float* ws    = (float*)d_ws;
    float* dense = ws;                               // 8192*512
    float* Qm    = dense + (size_t)NROWS * HID;      // 8192*256
    float* Km    = Qm    + (size_t)NROWS * DK;
    float* Vm    = Km    + (size_t)NROWS * DK;
    float* a_raw = Vm    + (size_t)NROWS * DK;       // 3*8192
    float* P     = a_raw + 3 * NROWS;                // 3*256
    float* Z     = P     + 3 * DK;                   // 3
    float* mx    = Z     + 3;                        // 3

    // Zero the atomic accumulators (P and Z are adjacent).
    hipMemsetAsync(P, 0, (3 * DK + 3) * sizeof(float), stream);

    // 1) dense = relu(X @ W1 + b1)
    {
        dim3 grid(HID / TN, NROWS / TM, 1);
        gemm3_f32<<<grid, 256, 0, stream>>>(
            X, W1, nullptr, nullptr, b1, nullptr, nullptr,
            dense, nullptr, nullptr, NROWS, HID, FEAT, 1);
    }
    // 2) Q/K/V = dense @ {Wq,Wk,Wv} (+bv on V)
    {
        dim3 grid(DK / TN, NROWS / TM, 3);
        gemm3_f32<<<grid, 256, 0, stream>>>(
            dense, Wq, Wk, Wv, nullptr, nullptr, bv,
            Qm, Km, Vm, NROWS, DK, HID, 0);
    }
    // 3) a_raw via gathered prefix K-sums
    gather_attn<<<NROWS, 64, 0, stream>>>(Qm, Km, sp, a_raw);
    // 4) per-selector max
    reduce_max_k<<<3, 1024, 0, stream>>>(a_raw, mx);
    // 5) pooled weighted sums
    {
        dim3 grid(NROWS / RPB, 3, 1);
        pool_kernel<<<grid, 256, 0, stream>>>(a_raw, mx, Vm, P, Z);
    }
    // 6) epilogue
    final_kernel<<<1, 256, 0, stream>>>(P, Z, Wout, bout, out);
}

// Round 2
// 105.545 us; speedup vs baseline: 2.5729x; 2.5729x over previous
//
#include <hip/hip_runtime.h>
#include <hip/hip_bf16.h>
#include <math.h>

#define FEAT 1024
#define HID  512
#define DK   256
#define NROWS 8192

typedef __attribute__((ext_vector_type(8))) short short8;
typedef __attribute__((ext_vector_type(4))) float floatx4;

// RNE float -> bf16 (raw u16), avoids hip_bf16 class in LDS/arrays.
__device__ __forceinline__ unsigned short f2bf(float x) {
    union { float f; unsigned u; } u;
    u.f = x;
    unsigned r = u.u;
    r += 0x7fffu + ((r >> 16) & 1u);
    return (unsigned short)(r >> 16);
}

__device__ __forceinline__ void gld_lds16(const unsigned short* g, unsigned short* l) {
    __builtin_amdgcn_global_load_lds(
        (__attribute__((address_space(1))) void*)(void*)g,
        (__attribute__((address_space(3))) void*)l,
        16, 0, 0);
}

// ---------------------------------------------------------------------------
// cast fp32 -> bf16, 4 elems/thread
// ---------------------------------------------------------------------------
__global__ __launch_bounds__(256) void cast_bf16(
    const float* __restrict__ in, unsigned short* __restrict__ out, int n4)
{
    int i = blockIdx.x * 256 + threadIdx.x;
    if (i >= n4) return;
    float4 v = ((const float4*)in)[i];
    ushort4 o;
    o.x = f2bf(v.x); o.y = f2bf(v.y); o.z = f2bf(v.z); o.w = f2bf(v.w);
    ((ushort4*)out)[i] = o;
}

// ---------------------------------------------------------------------------
// transpose + cast: in [K][N] fp32 -> out [N][K] bf16. block (32,8), 32x32 tile
// ---------------------------------------------------------------------------
__global__ __launch_bounds__(256) void transpose_cast(
    const float* __restrict__ in, unsigned short* __restrict__ out, int K, int N)
{
    __shared__ float t[32][33];
    const int n0 = blockIdx.x * 32, k0 = blockIdx.y * 32;
    const int tx = threadIdx.x, ty = threadIdx.y;
    #pragma unroll
    for (int i = ty; i < 32; i += 8)
        t[i][tx] = in[(size_t)(k0 + i) * N + (n0 + tx)];
    __syncthreads();
    #pragma unroll
    for (int i = ty; i < 32; i += 8)
        out[(size_t)(n0 + i) * K + (k0 + tx)] = f2bf(t[tx][i]);
}

// ---------------------------------------------------------------------------
// MFMA bf16 GEMM: C = [relu](A @ B^T + bias). A [M][K] bf16, BT [N][K] bf16.
// 128x128 tile, BK=32, 256 thr = 4 waves (2x2), 4x4 16x16x32 frags per wave.
// global_load_lds staging with 16B-granule XOR swizzle (g ^= (row>>1)&3) on
// the global source; same XOR on ds_read addr -> conflict-free ds_read_b128.
// blockIdx.z selects among up to 3 (BT, bias, C) for batched QKV.
// ---------------------------------------------------------------------------
template<int OUT_BF16>
__global__ __launch_bounds__(256) void gemm_mfma(
    const unsigned short* __restrict__ A,
    const unsigned short* __restrict__ BT0, const unsigned short* __restrict__ BT1,
    const unsigned short* __restrict__ BT2,
    const float* __restrict__ bias0, const float* __restrict__ bias1,
    const float* __restrict__ bias2,
    void* __restrict__ C0, void* __restrict__ C1, void* __restrict__ C2,
    int N, int K, int relu)
{
    const unsigned short* BT = (blockIdx.z == 0) ? BT0 : (blockIdx.z == 1) ? BT1 : BT2;
    const float* bias        = (blockIdx.z == 0) ? bias0 : (blockIdx.z == 1) ? bias1 : bias2;
    void* C                  = (blockIdx.z == 0) ? C0 : (blockIdx.z == 1) ? C1 : C2;

    __shared__ __align__(16) unsigned short As[128 * 32];
    __shared__ __align__(16) unsigned short Bs[128 * 32];

    const int tid  = threadIdx.x;
    const int lane = tid & 63;
    const int wid  = tid >> 6;
    const int wm = wid >> 1, wn = wid & 1;
    const int m0 = blockIdx.y * 128, n0 = blockIdx.x * 128;

    // Staging geometry: tile = 128 rows x 32 bf16 = 512 16B-granules.
    // granule idx -> (row = idx>>2, g = idx&3); source granule g ^ ((row>>1)&3).
    const int idx0 = wid * 64 + lane;
    const int idx1 = idx0 + 256;
    const int row0 = idx0 >> 2, g0 = idx0 & 3;
    const int row1 = idx1 >> 2, g1 = idx1 & 3;
    const int sg0 = g0 ^ ((row0 >> 1) & 3);
    const int sg1 = g1 ^ ((row1 >> 1) & 3);

    const unsigned short* Ap0 = A  + (size_t)(m0 + row0) * K + sg0 * 8;
    const unsigned short* Ap1 = A  + (size_t)(m0 + row1) * K + sg1 * 8;
    const unsigned short* Bp0 = BT + (size_t)(n0 + row0) * K + sg0 * 8;
    const unsigned short* Bp1 = BT + (size_t)(n0 + row1) * K + sg1 * 8;

    char* AsB = (char*)As;
    char* BsB = (char*)Bs;
    const int ldsOff0 = wid * 1024;        // wave-uniform LDS dest bases
    const int ldsOff1 = wid * 1024 + 4096;

    // Fragment ds_read byte offsets (swizzled).
    const int gr = lane >> 4;
    int aoff[4], boff[4];
    #pragma unroll
    for (int i = 0; i < 4; ++i) {
        int ra = wm * 64 + i * 16 + (lane & 15);
        aoff[i] = ra * 64 + ((gr ^ ((ra >> 1) & 3)) * 16);
        int rb = wn * 64 + i * 16 + (lane & 15);
        boff[i] = rb * 64 + ((gr ^ ((rb >> 1) & 3)) * 16);
    }

    floatx4 acc[4][4];
    #pragma unroll
    for (int i = 0; i < 4; ++i)
        #pragma unroll
        for (int j = 0; j < 4; ++j)
            acc[i][j] = (floatx4){0.f, 0.f, 0.f, 0.f};

    for (int kt = 0; kt < K; kt += 32) {
        gld_lds16(Ap0 + kt, (unsigned short*)(AsB + ldsOff0));
        gld_lds16(Ap1 + kt, (unsigned short*)(AsB + ldsOff1));
        gld_lds16(Bp0 + kt, (unsigned short*)(BsB + ldsOff0));
        gld_lds16(Bp1 + kt, (unsigned short*)(BsB + ldsOff1));
        __syncthreads();   // waits vmcnt(0): LDS tiles resident

        short8 af[4], bf[4];
        #pragma unroll
        for (int i = 0; i < 4; ++i) af[i] = *(const short8*)(AsB + aoff[i]);
        #pragma unroll
        for (int i = 0; i < 4; ++i) bf[i] = *(const short8*)(BsB + boff[i]);
        #pragma unroll
        for (int i = 0; i < 4; ++i)
            #pragma unroll
            for (int j = 0; j < 4; ++j)
                acc[i][j] = __builtin_amdgcn_mfma_f32_16x16x32_bf16(
                    af[i], bf[j], acc[i][j], 0, 0, 0);
        __syncthreads();   // protect LDS before next stage
    }

    // Epilogue: C/D layout col = lane&15, row = (lane>>4)*4 + reg.
    #pragma unroll
    for (int i = 0; i < 4; ++i) {
        int rbase = m0 + wm * 64 + i * 16 + (lane >> 4) * 4;
        #pragma unroll
        for (int j = 0; j < 4; ++j) {
            int c = n0 + wn * 64 + j * 16 + (lane & 15);
            float bb = bias ? bias[c] : 0.f;
            #pragma unroll
            for (int r = 0; r < 4; ++r) {
                float v = acc[i][j][r] + bb;
                if (relu) v = fmaxf(v, 0.f);
                if (OUT_BF16)
                    ((unsigned short*)C)[(size_t)(rbase + r) * N + c] = f2bf(v);
                else
                    ((float*)C)[(size_t)(rbase + r) * N + c] = v;
            }
        }
    }
}

// ---------------------------------------------------------------------------
// One wave per row i: gather 9 K-rows per sp_matrix, incremental prefix sums,
// a_raw[sel][i] = q_i . ksum / 16 at prefix lengths {3,5,9}.
// ---------------------------------------------------------------------------
__global__ __launch_bounds__(64) void gather_attn(
    const float* __restrict__ Q, const float* __restrict__ Kmat,
    const int* __restrict__ sp, float* __restrict__ a_raw)
{
    const int i = blockIdx.x;
    const int lane = threadIdx.x;

    float4 q = *(const float4*)(Q + (size_t)i * DK + lane * 4);
    float4 ks = make_float4(0.f, 0.f, 0.f, 0.f);

    int sel = 0;
    #pragma unroll
    for (int j = 0; j <= 8; ++j) {
        int r = sp[i * 9 + j];
        float4 kv = *(const float4*)(Kmat + (size_t)r * DK + lane * 4);
        ks.x += kv.x; ks.y += kv.y; ks.z += kv.z; ks.w += kv.w;
        if (j == 2 || j == 4 || j == 8) {
            float d = q.x * ks.x + q.y * ks.y + q.z * ks.z + q.w * ks.w;
            #pragma unroll
            for (int off = 32; off; off >>= 1) d += __shfl_xor(d, off);
            if (lane == 0) a_raw[sel * NROWS + i] = d * 0.0625f;  // /sqrt(256)
            ++sel;
        }
    }
}

__global__ __launch_bounds__(1024) void reduce_max_k(
    const float* __restrict__ a_raw, float* __restrict__ mx)
{
    __shared__ float s[1024];
    const int sel = blockIdx.x;
    float m = -INFINITY;
    for (int i = threadIdx.x; i < NROWS; i += 1024)
        m = fmaxf(m, a_raw[sel * NROWS + i]);
    s[threadIdx.x] = m;
    __syncthreads();
    for (int st = 512; st; st >>= 1) {
        if (threadIdx.x < st) s[threadIdx.x] = fmaxf(s[threadIdx.x], s[threadIdx.x + st]);
        __syncthreads();
    }
    if (threadIdx.x == 0) mx[sel] = s[0];
}

#define RPB 128
__global__ __launch_bounds__(256) void pool_kernel(
    const float* __restrict__ a_raw, const float* __restrict__ mx,
    const float* __restrict__ V, float* __restrict__ P, float* __restrict__ Z)
{
    const int sel = blockIdx.y;
    const int r0 = blockIdx.x * RPB;
    const int t = threadIdx.x;

    __shared__ float e[RPB];
    __shared__ float zs[4];

    const float m = mx[sel];
    float zp = 0.f;
    if (t < RPB) {
        float v = expf(a_raw[sel * NROWS + r0 + t] - m);
        e[t] = v;
        zp = v;
    }
    __syncthreads();

    float acc = 0.f;
    for (int r = 0; r < RPB; ++r)
        acc = fmaf(e[r], V[(size_t)(r0 + r) * DK + t], acc);
    atomicAdd(&P[sel * DK + t], acc);

    #pragma unroll
    for (int off = 32; off; off >>= 1) zp += __shfl_xor(zp, off);
    if ((t & 63) == 0) zs[t >> 6] = zp;
    __syncthreads();
    if (t == 0) atomicAdd(&Z[sel], zs[0] + zs[1] + zs[2] + zs[3]);
}

__global__ __launch_bounds__(256) void final_kernel(
    const float* __restrict__ P, const float* __restrict__ Z,
    const float* __restrict__ Wout, const float* __restrict__ bout,
    float* __restrict__ out)
{
    const int t = threadIdx.x;  // = d in 0..255
    float s = P[t] / Z[0] + P[DK + t] / Z[1] + P[2 * DK + t] / Z[2];
    __shared__ float s0[256], s1[256];
    s0[t] = s * Wout[t * 2 + 0];
    s1[t] = s * Wout[t * 2 + 1];
    __syncthreads();
    for (int st = 128; st; st >>= 1) {
        if (t < st) { s0[t] += s0[t + st]; s1[t] += s1[t + st]; }
        __syncthreads();
    }
    if (t == 0) {
        float a = s0[0] + bout[0], b = s1[0] + bout[1];
        float mm = fmaxf(a, b);
        float ea = expf(a - mm), eb = expf(b - mm);
        float inv = 1.f / (ea + eb);
        out[0] = ea * inv;
        out[1] = eb * inv;
    }
}

// ---------------------------------------------------------------------------
extern "C" void kernel_launch(void* const* d_in, const int* in_sizes, int n_in,
                              void* d_out, int out_size, void* d_ws, size_t ws_size,
                              hipStream_t stream)
{
    const float* X    = (const float*)d_in[0];   // 8192 x 1024
    const int*   sp   = (const int*)  d_in[1];   // 8192 x 9
    const float* W1   = (const float*)d_in[2];   // 1024 x 512
    const float* b1   = (const float*)d_in[3];   // 512
    const float* Wq   = (const float*)d_in[4];   // 512 x 256
    const float* Wk   = (const float*)d_in[5];
    const float* Wv   = (const float*)d_in[6];
    const float* bv   = (const float*)d_in[7];   // 256
    const float* Wout = (const float*)d_in[8];   // 256 x 2
    const float* bout = (const float*)d_in[9];   // 2
    float* out = (float*)d_out;

    // Workspace layout (bytes). Xb overlaps Qm/Km (dead before GEMM2 writes).
    char* w = (char*)d_ws;
    unsigned short* dense_b = (unsigned short*)(w);             // 8192x512 bf16  (8,388,608)
    unsigned short* W1T     = (unsigned short*)(w +  8388608);  // 512x1024 bf16  (1,048,576)
    unsigned short* WqT     = (unsigned short*)(w +  9437184);  // 256x512 bf16   (262,144)
    unsigned short* WkT     = (unsigned short*)(w +  9699328);
    unsigned short* WvT     = (unsigned short*)(w +  9961472);
    float* a_raw            = (float*)(w + 10223616);           // 3*8192 f32
    float* P                = (float*)(w + 10321920);           // 3*256 f32
    float* Z                = P + 3 * DK;                       // 3 (contiguous after P)
    float* mx               = Z + 3;                            // 3
    float* Qm               = (float*)(w + 10485760);           // 8192x256 f32 (8,388,608)
    float* Km               = (float*)(w + 18874368);
    float* Vm               = (float*)(w + 27262976);
    unsigned short* Xb      = (unsigned short*)(w + 10485760);  // 8192x1024 bf16 (16.8MB, overlaps Qm+Km)

    // Zero the atomic accumulators (P and Z are adjacent).
    hipMemsetAsync(P, 0, (3 * DK + 3) * sizeof(float), stream);

    // 0) casts / weight transposes
    cast_bf16<<<(NROWS * FEAT / 4 + 255) / 256, 256, 0, stream>>>(X, Xb, NROWS * FEAT / 4);
    {
        dim3 blk(32, 8);
        transpose_cast<<<dim3(HID / 32, FEAT / 32), blk, 0, stream>>>(W1, W1T, FEAT, HID);
        transpose_cast<<<dim3(DK / 32,  HID / 32),  blk, 0, stream>>>(Wq, WqT, HID, DK);
        transpose_cast<<<dim3(DK / 32,  HID / 32),  blk, 0, stream>>>(Wk, WkT, HID, DK);
        transpose_cast<<<dim3(DK / 32,  HID / 32),  blk, 0, stream>>>(Wv, WvT, HID, DK);
    }

    // 1) dense_b = bf16(relu(X @ W1 + b1))   [M=8192, N=512, K=1024]
    gemm_mfma<1><<<dim3(HID / 128, NROWS / 128, 1), 256, 0, stream>>>(
        Xb, W1T, nullptr, nullptr, b1, nullptr, nullptr,
        dense_b, nullptr, nullptr, HID, FEAT, 1);

    // 2) Q/K/V = dense @ {Wq,Wk,Wv} (+bv on V), fp32 out  [M=8192, N=256, K=512]
    gemm_mfma<0><<<dim3(DK / 128, NROWS / 128, 3), 256, 0, stream>>>(
        dense_b, WqT, WkT, WvT, nullptr, nullptr, bv,
        Qm, Km, Vm, DK, HID, 0);

    // 3) a_raw via gathered prefix K-sums
    gather_attn<<<NROWS, 64, 0, stream>>>(Qm, Km, sp, a_raw);
    // 4) per-selector max
    reduce_max_k<<<3, 1024, 0, stream>>>(a_raw, mx);
    // 5) pooled weighted sums
    pool_kernel<<<dim3(NROWS / RPB, 3, 1), 256, 0, stream>>>(a_raw, mx, Vm, P, Z);
    // 6) epilogue
    final_kernel<<<1, 256, 0, stream>>>(P, Z, Wout, bout, out);
}

// Round 3
// 90.491 us; speedup vs baseline: 3.0010x; 1.1664x over previous
//
#include <hip/hip_runtime.h>
#include <hip/hip_bf16.h>
#include <math.h>

#define FEAT 1024
#define HID  512
#define DK   256
#define NROWS 8192

typedef __attribute__((ext_vector_type(8))) short short8;
typedef __attribute__((ext_vector_type(4))) float floatx4;

// RNE float -> bf16 (raw u16), avoids hip_bf16 class in LDS/arrays.
__device__ __forceinline__ unsigned short f2bf(float x) {
    union { float f; unsigned u; } u;
    u.f = x;
    unsigned r = u.u;
    r += 0x7fffu + ((r >> 16) & 1u);
    return (unsigned short)(r >> 16);
}

__device__ __forceinline__ void gld_lds16(const unsigned short* g, unsigned short* l) {
    __builtin_amdgcn_global_load_lds(
        (__attribute__((address_space(1))) void*)(void*)g,
        (__attribute__((address_space(3))) void*)l,
        16, 0, 0);
}

// ---------------------------------------------------------------------------
// cast fp32 -> bf16, 4 elems/thread
// ---------------------------------------------------------------------------
__global__ __launch_bounds__(256) void cast_bf16(
    const float* __restrict__ in, unsigned short* __restrict__ out, int n4)
{
    int i = blockIdx.x * 256 + threadIdx.x;
    if (i >= n4) return;
    float4 v = ((const float4*)in)[i];
    ushort4 o;
    o.x = f2bf(v.x); o.y = f2bf(v.y); o.z = f2bf(v.z); o.w = f2bf(v.w);
    ((ushort4*)out)[i] = o;
}

// ---------------------------------------------------------------------------
// All four weight transposes in one launch. in [K][N] f32 -> out [N][K] bf16.
// blockIdx.z: 0 -> W1 (1024x512), 1..3 -> Wq/Wk/Wv (512x256).
// ---------------------------------------------------------------------------
__global__ __launch_bounds__(256) void transpose_cast4(
    const float* __restrict__ W1, const float* __restrict__ Wq,
    const float* __restrict__ Wk, const float* __restrict__ Wv,
    unsigned short* __restrict__ W1T, unsigned short* __restrict__ WqT,
    unsigned short* __restrict__ WkT, unsigned short* __restrict__ WvT)
{
    const int z = blockIdx.z;
    const float* in; unsigned short* out; int K, N;
    if (z == 0)      { in = W1; out = W1T; K = FEAT; N = HID; }
    else if (z == 1) { in = Wq; out = WqT; K = HID;  N = DK;  }
    else if (z == 2) { in = Wk; out = WkT; K = HID;  N = DK;  }
    else             { in = Wv; out = WvT; K = HID;  N = DK;  }

    const int n0 = blockIdx.x * 32, k0 = blockIdx.y * 32;
    if (n0 >= N || k0 >= K) return;

    __shared__ float t[32][33];
    const int tx = threadIdx.x, ty = threadIdx.y;
    #pragma unroll
    for (int i = ty; i < 32; i += 8)
        t[i][tx] = in[(size_t)(k0 + i) * N + (n0 + tx)];
    __syncthreads();
    #pragma unroll
    for (int i = ty; i < 32; i += 8)
        out[(size_t)(n0 + i) * K + (k0 + tx)] = f2bf(t[tx][i]);
}

// ---------------------------------------------------------------------------
// MFMA bf16 GEMM: C = [relu](A @ B^T + bias). A [M][K] bf16, BT [N][K] bf16.
// 128x128 tile, BK=32, 256 thr = 4 waves (2x2), 4x4 16x16x32 frags per wave.
// global_load_lds staging with 16B-granule XOR swizzle (g ^= (row>>1)&3) on
// the global source; same XOR on ds_read addr -> conflict-free ds_read_b128.
// blockIdx.z selects among up to 3 (BT, bias, C) for batched QKV.
// ---------------------------------------------------------------------------
template<int OUT_BF16>
__global__ __launch_bounds__(256) void gemm_mfma(
    const unsigned short* __restrict__ A,
    const unsigned short* __restrict__ BT0, const unsigned short* __restrict__ BT1,
    const unsigned short* __restrict__ BT2,
    const float* __restrict__ bias0, const float* __restrict__ bias1,
    const float* __restrict__ bias2,
    void* __restrict__ C0, void* __restrict__ C1, void* __restrict__ C2,
    int N, int K, int relu)
{
    const unsigned short* BT = (blockIdx.z == 0) ? BT0 : (blockIdx.z == 1) ? BT1 : BT2;
    const float* bias        = (blockIdx.z == 0) ? bias0 : (blockIdx.z == 1) ? bias1 : bias2;
    void* C                  = (blockIdx.z == 0) ? C0 : (blockIdx.z == 1) ? C1 : C2;

    __shared__ __align__(16) unsigned short As[128 * 32];
    __shared__ __align__(16) unsigned short Bs[128 * 32];

    const int tid  = threadIdx.x;
    const int lane = tid & 63;
    const int wid  = tid >> 6;
    const int wm = wid >> 1, wn = wid & 1;
    const int m0 = blockIdx.y * 128, n0 = blockIdx.x * 128;

    // Staging geometry: tile = 128 rows x 32 bf16 = 512 16B-granules.
    // granule idx -> (row = idx>>2, g = idx&3); source granule g ^ ((row>>1)&3).
    const int idx0 = wid * 64 + lane;
    const int idx1 = idx0 + 256;
    const int row0 = idx0 >> 2, g0 = idx0 & 3;
    const int row1 = idx1 >> 2, g1 = idx1 & 3;
    const int sg0 = g0 ^ ((row0 >> 1) & 3);
    const int sg1 = g1 ^ ((row1 >> 1) & 3);

    const unsigned short* Ap0 = A  + (size_t)(m0 + row0) * K + sg0 * 8;
    const unsigned short* Ap1 = A  + (size_t)(m0 + row1) * K + sg1 * 8;
    const unsigned short* Bp0 = BT + (size_t)(n0 + row0) * K + sg0 * 8;
    const unsigned short* Bp1 = BT + (size_t)(n0 + row1) * K + sg1 * 8;

    char* AsB = (char*)As;
    char* BsB = (char*)Bs;
    const int ldsOff0 = wid * 1024;        // wave-uniform LDS dest bases
    const int ldsOff1 = wid * 1024 + 4096;

    // Fragment ds_read byte offsets (swizzled).
    const int gr = lane >> 4;
    int aoff[4], boff[4];
    #pragma unroll
    for (int i = 0; i < 4; ++i) {
        int ra = wm * 64 + i * 16 + (lane & 15);
        aoff[i] = ra * 64 + ((gr ^ ((ra >> 1) & 3)) * 16);
        int rb = wn * 64 + i * 16 + (lane & 15);
        boff[i] = rb * 64 + ((gr ^ ((rb >> 1) & 3)) * 16);
    }

    floatx4 acc[4][4];
    #pragma unroll
    for (int i = 0; i < 4; ++i)
        #pragma unroll
        for (int j = 0; j < 4; ++j)
            acc[i][j] = (floatx4){0.f, 0.f, 0.f, 0.f};

    for (int kt = 0; kt < K; kt += 32) {
        gld_lds16(Ap0 + kt, (unsigned short*)(AsB + ldsOff0));
        gld_lds16(Ap1 + kt, (unsigned short*)(AsB + ldsOff1));
        gld_lds16(Bp0 + kt, (unsigned short*)(BsB + ldsOff0));
        gld_lds16(Bp1 + kt, (unsigned short*)(BsB + ldsOff1));
        __syncthreads();   // waits vmcnt(0): LDS tiles resident

        short8 af[4], bf[4];
        #pragma unroll
        for (int i = 0; i < 4; ++i) af[i] = *(const short8*)(AsB + aoff[i]);
        #pragma unroll
        for (int i = 0; i < 4; ++i) bf[i] = *(const short8*)(BsB + boff[i]);
        #pragma unroll
        for (int i = 0; i < 4; ++i)
            #pragma unroll
            for (int j = 0; j < 4; ++j)
                acc[i][j] = __builtin_amdgcn_mfma_f32_16x16x32_bf16(
                    af[i], bf[j], acc[i][j], 0, 0, 0);
        __syncthreads();   // protect LDS before next stage
    }

    // Epilogue: C/D layout col = lane&15, row = (lane>>4)*4 + reg.
    #pragma unroll
    for (int i = 0; i < 4; ++i) {
        int rbase = m0 + wm * 64 + i * 16 + (lane >> 4) * 4;
        #pragma unroll
        for (int j = 0; j < 4; ++j) {
            int c = n0 + wn * 64 + j * 16 + (lane & 15);
            float bb = bias ? bias[c] : 0.f;
            #pragma unroll
            for (int r = 0; r < 4; ++r) {
                float v = acc[i][j][r] + bb;
                if (relu) v = fmaxf(v, 0.f);
                if (OUT_BF16)
                    ((unsigned short*)C)[(size_t)(rbase + r) * N + c] = f2bf(v);
                else
                    ((float*)C)[(size_t)(rbase + r) * N + c] = v;
            }
        }
    }
}

// ---------------------------------------------------------------------------
// One wave per row i: gather 9 K-rows per sp_matrix, incremental prefix sums,
// a_raw[sel][i] = q_i . ksum / 16 at prefix lengths {3,5,9}.
// ---------------------------------------------------------------------------
__global__ __launch_bounds__(64) void gather_attn(
    const float* __restrict__ Q, const float* __restrict__ Kmat,
    const int* __restrict__ sp, float* __restrict__ a_raw)
{
    const int i = blockIdx.x;
    const int lane = threadIdx.x;

    float4 q = *(const float4*)(Q + (size_t)i * DK + lane * 4);
    float4 ks = make_float4(0.f, 0.f, 0.f, 0.f);

    int sel = 0;
    #pragma unroll
    for (int j = 0; j <= 8; ++j) {
        int r = sp[i * 9 + j];
        float4 kv = *(const float4*)(Kmat + (size_t)r * DK + lane * 4);
        ks.x += kv.x; ks.y += kv.y; ks.z += kv.z; ks.w += kv.w;
        if (j == 2 || j == 4 || j == 8) {
            float d = q.x * ks.x + q.y * ks.y + q.z * ks.z + q.w * ks.w;
            #pragma unroll
            for (int off = 32; off; off >>= 1) d += __shfl_xor(d, off);
            if (lane == 0) a_raw[sel * NROWS + i] = d * 0.0625f;  // /sqrt(256)
            ++sel;
        }
    }
}

// ---------------------------------------------------------------------------
// Max over N per selector (3 blocks). Also zeroes the P/Z atomic accumulators
// (replaces the pathological hipMemsetAsync fill in the graph).
// ---------------------------------------------------------------------------
__global__ __launch_bounds__(1024) void reduce_max_k(
    const float* __restrict__ a_raw, float* __restrict__ mx,
    float* __restrict__ P, float* __restrict__ Z)
{
    __shared__ float s[1024];
    const int sel = blockIdx.x;
    if (threadIdx.x < DK) P[sel * DK + threadIdx.x] = 0.f;
    if (threadIdx.x == 0) Z[sel] = 0.f;
    float m = -INFINITY;
    for (int i = threadIdx.x; i < NROWS; i += 1024)
        m = fmaxf(m, a_raw[sel * NROWS + i]);
    s[threadIdx.x] = m;
    __syncthreads();
    for (int st = 512; st; st >>= 1) {
        if (threadIdx.x < st) s[threadIdx.x] = fmaxf(s[threadIdx.x], s[threadIdx.x + st]);
        __syncthreads();
    }
    if (threadIdx.x == 0) mx[sel] = s[0];
}

#define RPB 128
__global__ __launch_bounds__(256) void pool_kernel(
    const float* __restrict__ a_raw, const float* __restrict__ mx,
    const float* __restrict__ V, float* __restrict__ P, float* __restrict__ Z)
{
    const int sel = blockIdx.y;
    const int r0 = blockIdx.x * RPB;
    const int t = threadIdx.x;

    __shared__ float e[RPB];
    __shared__ float zs[4];

    const float m = mx[sel];
    float zp = 0.f;
    if (t < RPB) {
        float v = expf(a_raw[sel * NROWS + r0 + t] - m);
        e[t] = v;
        zp = v;
    }
    __syncthreads();

    float acc = 0.f;
    for (int r = 0; r < RPB; ++r)
        acc = fmaf(e[r], V[(size_t)(r0 + r) * DK + t], acc);
    atomicAdd(&P[sel * DK + t], acc);

    #pragma unroll
    for (int off = 32; off; off >>= 1) zp += __shfl_xor(zp, off);
    if ((t & 63) == 0) zs[t >> 6] = zp;
    __syncthreads();
    if (t == 0) atomicAdd(&Z[sel], zs[0] + zs[1] + zs[2] + zs[3]);
}

__global__ __launch_bounds__(256) void final_kernel(
    const float* __restrict__ P, const float* __restrict__ Z,
    const float* __restrict__ Wout, const float* __restrict__ bout,
    float* __restrict__ out)
{
    const int t = threadIdx.x;  // = d in 0..255
    float s = P[t] / Z[0] + P[DK + t] / Z[1] + P[2 * DK + t] / Z[2];
    __shared__ float s0[256], s1[256];
    s0[t] = s * Wout[t * 2 + 0];
    s1[t] = s * Wout[t * 2 + 1];
    __syncthreads();
    for (int st = 128; st; st >>= 1) {
        if (t < st) { s0[t] += s0[t + st]; s1[t] += s1[t + st]; }
        __syncthreads();
    }
    if (t == 0) {
        float a = s0[0] + bout[0], b = s1[0] + bout[1];
        float mm = fmaxf(a, b);
        float ea = expf(a - mm), eb = expf(b - mm);
        float inv = 1.f / (ea + eb);
        out[0] = ea * inv;
        out[1] = eb * inv;
    }
}

// ---------------------------------------------------------------------------
extern "C" void kernel_launch(void* const* d_in, const int* in_sizes, int n_in,
                              void* d_out, int out_size, void* d_ws, size_t ws_size,
                              hipStream_t stream)
{
    const float* X    = (const float*)d_in[0];   // 8192 x 1024
    const int*   sp   = (const int*)  d_in[1];   // 8192 x 9
    const float* W1   = (const float*)d_in[2];   // 1024 x 512
    const float* b1   = (const float*)d_in[3];   // 512
    const float* Wq   = (const float*)d_in[4];   // 512 x 256
    const float* Wk   = (const float*)d_in[5];
    const float* Wv   = (const float*)d_in[6];
    const float* bv   = (const float*)d_in[7];   // 256
    const float* Wout = (const float*)d_in[8];   // 256 x 2
    const float* bout = (const float*)d_in[9];   // 2
    float* out = (float*)d_out;

    // Workspace layout (bytes). Xb overlaps Qm/Km (dead before GEMM2 writes).
    char* w = (char*)d_ws;
    unsigned short* dense_b = (unsigned short*)(w);             // 8192x512 bf16  (8,388,608)
    unsigned short* W1T     = (unsigned short*)(w +  8388608);  // 512x1024 bf16  (1,048,576)
    unsigned short* WqT     = (unsigned short*)(w +  9437184);  // 256x512 bf16   (262,144)
    unsigned short* WkT     = (unsigned short*)(w +  9699328);
    unsigned short* WvT     = (unsigned short*)(w +  9961472);
    float* a_raw            = (float*)(w + 10223616);           // 3*8192 f32
    float* P                = (float*)(w + 10321920);           // 3*256 f32
    float* Z                = P + 3 * DK;                       // 3 (contiguous after P)
    float* mx               = Z + 3;                            // 3
    float* Qm               = (float*)(w + 10485760);           // 8192x256 f32 (8,388,608)
    float* Km               = (float*)(w + 18874368);
    float* Vm               = (float*)(w + 27262976);
    unsigned short* Xb      = (unsigned short*)(w + 10485760);  // 8192x1024 bf16 (16.8MB, overlaps Qm+Km)

    // 0) casts / weight transposes (single launch for all 4 weights)
    cast_bf16<<<(NROWS * FEAT / 4 + 255) / 256, 256, 0, stream>>>(X, Xb, NROWS * FEAT / 4);
    transpose_cast4<<<dim3(16, 32, 4), dim3(32, 8), 0, stream>>>(
        W1, Wq, Wk, Wv, W1T, WqT, WkT, WvT);

    // 1) dense_b = bf16(relu(X @ W1 + b1))   [M=8192, N=512, K=1024]
    gemm_mfma<1><<<dim3(HID / 128, NROWS / 128, 1), 256, 0, stream>>>(
        Xb, W1T, nullptr, nullptr, b1, nullptr, nullptr,
        dense_b, nullptr, nullptr, HID, FEAT, 1);

    // 2) Q/K/V = dense @ {Wq,Wk,Wv} (+bv on V), fp32 out  [M=8192, N=256, K=512]
    gemm_mfma<0><<<dim3(DK / 128, NROWS / 128, 3), 256, 0, stream>>>(
        dense_b, WqT, WkT, WvT, nullptr, nullptr, bv,
        Qm, Km, Vm, DK, HID, 0);

    // 3) a_raw via gathered prefix K-sums
    gather_attn<<<NROWS, 64, 0, stream>>>(Qm, Km, sp, a_raw);
    // 4) per-selector max + zero P/Z accumulators
    reduce_max_k<<<3, 1024, 0, stream>>>(a_raw, mx, P, Z);
    // 5) pooled weighted sums
    pool_kernel<<<dim3(NROWS / RPB, 3, 1), 256, 0, stream>>>(a_raw, mx, Vm, P, Z);
    // 6) epilogue
    final_kernel<<<1, 256, 0, stream>>>(P, Z, Wout, bout, out);
}

// Round 4
// 76.545 us; speedup vs baseline: 3.5477x; 1.1822x over previous
//
#include <hip/hip_runtime.h>
#include <hip/hip_bf16.h>
#include <math.h>

#define FEAT 1024
#define HID  512
#define DK   256
#define NROWS 8192

typedef __attribute__((ext_vector_type(8))) short short8;
typedef __attribute__((ext_vector_type(4))) float floatx4;

// RNE float -> bf16 (raw u16).
__device__ __forceinline__ unsigned short f2bf(float x) {
    union { float f; unsigned u; } u;
    u.f = x;
    unsigned r = u.u;
    r += 0x7fffu + ((r >> 16) & 1u);
    return (unsigned short)(r >> 16);
}
__device__ __forceinline__ float bf2f(unsigned short x) {
    union { unsigned u; float f; } u;
    u.u = ((unsigned)x) << 16;
    return u.f;
}

__device__ __forceinline__ void gld_lds16(const unsigned short* g, unsigned short* l) {
    __builtin_amdgcn_global_load_lds(
        (__attribute__((address_space(1))) void*)(void*)g,
        (__attribute__((address_space(3))) void*)l,
        16, 0, 0);
}

// ---------------------------------------------------------------------------
// cast fp32 -> bf16, 4 elems/thread
// ---------------------------------------------------------------------------
__global__ __launch_bounds__(256) void cast_bf16(
    const float* __restrict__ in, unsigned short* __restrict__ out, int n4)
{
    int i = blockIdx.x * 256 + threadIdx.x;
    if (i >= n4) return;
    float4 v = ((const float4*)in)[i];
    ushort4 o;
    o.x = f2bf(v.x); o.y = f2bf(v.y); o.z = f2bf(v.z); o.w = f2bf(v.w);
    ((ushort4*)out)[i] = o;
}

// ---------------------------------------------------------------------------
// All four weight transposes in one launch. in [K][N] f32 -> out [N][K] bf16.
// blockIdx.z: 0 -> W1 (1024x512), 1..3 -> Wq/Wk/Wv (512x256).
// ---------------------------------------------------------------------------
__global__ __launch_bounds__(256) void transpose_cast4(
    const float* __restrict__ W1, const float* __restrict__ Wq,
    const float* __restrict__ Wk, const float* __restrict__ Wv,
    unsigned short* __restrict__ W1T, unsigned short* __restrict__ WqT,
    unsigned short* __restrict__ WkT, unsigned short* __restrict__ WvT)
{
    const int z = blockIdx.z;
    const float* in; unsigned short* out; int K, N;
    if (z == 0)      { in = W1; out = W1T; K = FEAT; N = HID; }
    else if (z == 1) { in = Wq; out = WqT; K = HID;  N = DK;  }
    else if (z == 2) { in = Wk; out = WkT; K = HID;  N = DK;  }
    else             { in = Wv; out = WvT; K = HID;  N = DK;  }

    const int n0 = blockIdx.x * 32, k0 = blockIdx.y * 32;
    if (n0 >= N || k0 >= K) return;

    __shared__ float t[32][33];
    const int tx = threadIdx.x, ty = threadIdx.y;
    #pragma unroll
    for (int i = ty; i < 32; i += 8)
        t[i][tx] = in[(size_t)(k0 + i) * N + (n0 + tx)];
    __syncthreads();
    #pragma unroll
    for (int i = ty; i < 32; i += 8)
        out[(size_t)(n0 + i) * K + (k0 + tx)] = f2bf(t[tx][i]);
}

// ---------------------------------------------------------------------------
// MFMA bf16 GEMM: C = bf16([relu](A @ B^T + bias)). A [M][K] bf16, BT [N][K].
// 64x128 tile, BK=32, 256 thr = 4 waves (2x2), per-wave 2x4 16x16x32 frags.
// Grid is 2-3 blocks/CU so inter-block overlap hides the per-tile barrier
// drain. global_load_lds staging with 16B-granule XOR swizzle on the global
// source; same XOR on ds_read addr. blockIdx.z batches up to 3 (BT,bias,C).
// ---------------------------------------------------------------------------
__global__ __launch_bounds__(256) void gemm_mfma(
    const unsigned short* __restrict__ A,
    const unsigned short* __restrict__ BT0, const unsigned short* __restrict__ BT1,
    const unsigned short* __restrict__ BT2,
    const float* __restrict__ bias0, const float* __restrict__ bias1,
    const float* __restrict__ bias2,
    unsigned short* __restrict__ C0, unsigned short* __restrict__ C1,
    unsigned short* __restrict__ C2,
    int N, int K, int relu)
{
    const unsigned short* BT = (blockIdx.z == 0) ? BT0 : (blockIdx.z == 1) ? BT1 : BT2;
    const float* bias        = (blockIdx.z == 0) ? bias0 : (blockIdx.z == 1) ? bias1 : bias2;
    unsigned short* C        = (blockIdx.z == 0) ? C0 : (blockIdx.z == 1) ? C1 : C2;

    __shared__ __align__(16) unsigned short As[64 * 32];    // 4 KB
    __shared__ __align__(16) unsigned short Bs[128 * 32];   // 8 KB

    const int tid  = threadIdx.x;
    const int lane = tid & 63;
    const int wid  = tid >> 6;
    const int wm = wid >> 1, wn = wid & 1;
    const int m0 = blockIdx.y * 64, n0 = blockIdx.x * 128;

    // A staging: 64 rows x 4 granules = 256 granules, 1/thread.
    const int rowA = tid >> 2, gA = tid & 3;
    const int sgA = gA ^ ((rowA >> 1) & 3);
    const unsigned short* Ap = A + (size_t)(m0 + rowA) * K + sgA * 8;

    // B staging: 128 rows x 4 granules = 512 granules, 2/thread.
    const int idx0 = tid, idx1 = tid + 256;
    const int rowB0 = idx0 >> 2, gB0 = idx0 & 3;
    const int rowB1 = idx1 >> 2, gB1 = idx1 & 3;
    const int sgB0 = gB0 ^ ((rowB0 >> 1) & 3);
    const int sgB1 = gB1 ^ ((rowB1 >> 1) & 3);
    const unsigned short* Bp0 = BT + (size_t)(n0 + rowB0) * K + sgB0 * 8;
    const unsigned short* Bp1 = BT + (size_t)(n0 + rowB1) * K + sgB1 * 8;

    char* AsB = (char*)As;
    char* BsB = (char*)Bs;
    const int ldsA  = wid * 1024;          // wave-uniform dest bases
    const int ldsB0 = wid * 1024;
    const int ldsB1 = wid * 1024 + 4096;

    // Fragment ds_read byte offsets (swizzled).
    const int gr = lane >> 4;
    int aoff[2], boff[4];
    #pragma unroll
    for (int i = 0; i < 2; ++i) {
        int ra = wm * 32 + i * 16 + (lane & 15);
        aoff[i] = ra * 64 + ((gr ^ ((ra >> 1) & 3)) * 16);
    }
    #pragma unroll
    for (int j = 0; j < 4; ++j) {
        int rb = wn * 64 + j * 16 + (lane & 15);
        boff[j] = rb * 64 + ((gr ^ ((rb >> 1) & 3)) * 16);
    }

    floatx4 acc[2][4];
    #pragma unroll
    for (int i = 0; i < 2; ++i)
        #pragma unroll
        for (int j = 0; j < 4; ++j)
            acc[i][j] = (floatx4){0.f, 0.f, 0.f, 0.f};

    for (int kt = 0; kt < K; kt += 32) {
        gld_lds16(Ap  + kt, (unsigned short*)(AsB + ldsA));
        gld_lds16(Bp0 + kt, (unsigned short*)(BsB + ldsB0));
        gld_lds16(Bp1 + kt, (unsigned short*)(BsB + ldsB1));
        __syncthreads();   // waits vmcnt(0): LDS tiles resident

        short8 af[2], bfr[4];
        #pragma unroll
        for (int i = 0; i < 2; ++i) af[i] = *(const short8*)(AsB + aoff[i]);
        #pragma unroll
        for (int j = 0; j < 4; ++j) bfr[j] = *(const short8*)(BsB + boff[j]);
        #pragma unroll
        for (int i = 0; i < 2; ++i)
            #pragma unroll
            for (int j = 0; j < 4; ++j)
                acc[i][j] = __builtin_amdgcn_mfma_f32_16x16x32_bf16(
                    af[i], bfr[j], acc[i][j], 0, 0, 0);
        __syncthreads();   // protect LDS before next stage
    }

    // Epilogue: C/D layout col = lane&15, row = (lane>>4)*4 + reg. bf16 out.
    #pragma unroll
    for (int i = 0; i < 2; ++i) {
        int rbase = m0 + wm * 32 + i * 16 + (lane >> 4) * 4;
        #pragma unroll
        for (int j = 0; j < 4; ++j) {
            int c = n0 + wn * 64 + j * 16 + (lane & 15);
            float bb = bias ? bias[c] : 0.f;
            #pragma unroll
            for (int r = 0; r < 4; ++r) {
                float v = acc[i][j][r] + bb;
                if (relu) v = fmaxf(v, 0.f);
                C[(size_t)(rbase + r) * N + c] = f2bf(v);
            }
        }
    }
}

// ---------------------------------------------------------------------------
// One wave per row i: gather 9 K-rows (bf16) per sp_matrix, incremental
// prefix sums in fp32, a_raw[sel][i] = q_i . ksum / 16 at lengths {3,5,9}.
// ---------------------------------------------------------------------------
__global__ __launch_bounds__(64) void gather_attn(
    const unsigned short* __restrict__ Q, const unsigned short* __restrict__ Kmat,
    const int* __restrict__ sp, float* __restrict__ a_raw)
{
    const int i = blockIdx.x;
    const int lane = threadIdx.x;

    ushort4 qr = *(const ushort4*)(Q + (size_t)i * DK + lane * 4);
    float4 q = make_float4(bf2f(qr.x), bf2f(qr.y), bf2f(qr.z), bf2f(qr.w));
    float4 ks = make_float4(0.f, 0.f, 0.f, 0.f);

    int sel = 0;
    #pragma unroll
    for (int j = 0; j <= 8; ++j) {
        int r = sp[i * 9 + j];
        ushort4 kr = *(const ushort4*)(Kmat + (size_t)r * DK + lane * 4);
        ks.x += bf2f(kr.x); ks.y += bf2f(kr.y);
        ks.z += bf2f(kr.z); ks.w += bf2f(kr.w);
        if (j == 2 || j == 4 || j == 8) {
            float d = q.x * ks.x + q.y * ks.y + q.z * ks.z + q.w * ks.w;
            #pragma unroll
            for (int off = 32; off; off >>= 1) d += __shfl_xor(d, off);
            if (lane == 0) a_raw[sel * NROWS + i] = d * 0.0625f;  // /sqrt(256)
            ++sel;
        }
    }
}

// ---------------------------------------------------------------------------
// Max over N per selector (3 blocks). Also zeroes P/Z atomic accumulators.
// ---------------------------------------------------------------------------
__global__ __launch_bounds__(1024) void reduce_max_k(
    const float* __restrict__ a_raw, float* __restrict__ mx,
    float* __restrict__ P, float* __restrict__ Z)
{
    __shared__ float s[1024];
    const int sel = blockIdx.x;
    if (threadIdx.x < DK) P[sel * DK + threadIdx.x] = 0.f;
    if (threadIdx.x == 0) Z[sel] = 0.f;
    float m = -INFINITY;
    for (int i = threadIdx.x; i < NROWS; i += 1024)
        m = fmaxf(m, a_raw[sel * NROWS + i]);
    s[threadIdx.x] = m;
    __syncthreads();
    for (int st = 512; st; st >>= 1) {
        if (threadIdx.x < st) s[threadIdx.x] = fmaxf(s[threadIdx.x], s[threadIdx.x + st]);
        __syncthreads();
    }
    if (threadIdx.x == 0) mx[sel] = s[0];
}

#define RPB 128
__global__ __launch_bounds__(256) void pool_kernel(
    const float* __restrict__ a_raw, const float* __restrict__ mx,
    const unsigned short* __restrict__ V, float* __restrict__ P,
    float* __restrict__ Z)
{
    const int sel = blockIdx.y;
    const int r0 = blockIdx.x * RPB;
    const int t = threadIdx.x;

    __shared__ float e[RPB];
    __shared__ float zs[4];

    const float m = mx[sel];
    float zp = 0.f;
    if (t < RPB) {
        float v = expf(a_raw[sel * NROWS + r0 + t] - m);
        e[t] = v;
        zp = v;
    }
    __syncthreads();

    float acc = 0.f;
    for (int r = 0; r < RPB; ++r)
        acc = fmaf(e[r], bf2f(V[(size_t)(r0 + r) * DK + t]), acc);
    atomicAdd(&P[sel * DK + t], acc);

    #pragma unroll
    for (int off = 32; off; off >>= 1) zp += __shfl_xor(zp, off);
    if ((t & 63) == 0) zs[t >> 6] = zp;
    __syncthreads();
    if (t == 0) atomicAdd(&Z[sel], zs[0] + zs[1] + zs[2] + zs[3]);
}

__global__ __launch_bounds__(256) void final_kernel(
    const float* __restrict__ P, const float* __restrict__ Z,
    const float* __restrict__ Wout, const float* __restrict__ bout,
    float* __restrict__ out)
{
    const int t = threadIdx.x;  // = d in 0..255
    float s = P[t] / Z[0] + P[DK + t] / Z[1] + P[2 * DK + t] / Z[2];
    __shared__ float s0[256], s1[256];
    s0[t] = s * Wout[t * 2 + 0];
    s1[t] = s * Wout[t * 2 + 1];
    __syncthreads();
    for (int st = 128; st; st >>= 1) {
        if (t < st) { s0[t] += s0[t + st]; s1[t] += s1[t + st]; }
        __syncthreads();
    }
    if (t == 0) {
        float a = s0[0] + bout[0], b = s1[0] + bout[1];
        float mm = fmaxf(a, b);
        float ea = expf(a - mm), eb = expf(b - mm);
        float inv = 1.f / (ea + eb);
        out[0] = ea * inv;
        out[1] = eb * inv;
    }
}

// ---------------------------------------------------------------------------
extern "C" void kernel_launch(void* const* d_in, const int* in_sizes, int n_in,
                              void* d_out, int out_size, void* d_ws, size_t ws_size,
                              hipStream_t stream)
{
    const float* X    = (const float*)d_in[0];   // 8192 x 1024
    const int*   sp   = (const int*)  d_in[1];   // 8192 x 9
    const float* W1   = (const float*)d_in[2];   // 1024 x 512
    const float* b1   = (const float*)d_in[3];   // 512
    const float* Wq   = (const float*)d_in[4];   // 512 x 256
    const float* Wk   = (const float*)d_in[5];
    const float* Wv   = (const float*)d_in[6];
    const float* bv   = (const float*)d_in[7];   // 256
    const float* Wout = (const float*)d_in[8];   // 256 x 2
    const float* bout = (const float*)d_in[9];   // 2
    float* out = (float*)d_out;

    // Workspace layout (bytes). Xb (16.8 MB) overlaps Qb/Kb/Vb + slack —
    // Xb is dead before GEMM2 writes them.
    char* w = (char*)d_ws;
    unsigned short* dense_b = (unsigned short*)(w);             // 8192x512 bf16
    unsigned short* W1T     = (unsigned short*)(w +  8388608);  // 512x1024 bf16
    unsigned short* WqT     = (unsigned short*)(w +  9437184);  // 256x512 bf16
    unsigned short* WkT     = (unsigned short*)(w +  9699328);
    unsigned short* WvT     = (unsigned short*)(w +  9961472);
    float* a_raw            = (float*)(w + 10223616);           // 3*8192 f32
    float* P                = (float*)(w + 10321920);           // 3*256 f32
    float* Z                = P + 3 * DK;
    float* mx               = Z + 3;
    unsigned short* Qb      = (unsigned short*)(w + 10485760);  // 8192x256 bf16
    unsigned short* Kb      = (unsigned short*)(w + 14680064);
    unsigned short* Vb      = (unsigned short*)(w + 18874368);
    unsigned short* Xb      = (unsigned short*)(w + 10485760);  // 8192x1024 bf16

    // 0) casts / weight transposes
    cast_bf16<<<(NROWS * FEAT / 4 + 255) / 256, 256, 0, stream>>>(X, Xb, NROWS * FEAT / 4);
    transpose_cast4<<<dim3(16, 32, 4), dim3(32, 8), 0, stream>>>(
        W1, Wq, Wk, Wv, W1T, WqT, WkT, WvT);

    // 1) dense_b = bf16(relu(X @ W1 + b1))   [M=8192, N=512, K=1024]
    gemm_mfma<<<dim3(HID / 128, NROWS / 64, 1), 256, 0, stream>>>(
        Xb, W1T, nullptr, nullptr, b1, nullptr, nullptr,
        dense_b, nullptr, nullptr, HID, FEAT, 1);

    // 2) Q/K/V = bf16(dense @ {Wq,Wk,Wv} (+bv on V))  [M=8192, N=256, K=512]
    gemm_mfma<<<dim3(DK / 128, NROWS / 64, 3), 256, 0, stream>>>(
        dense_b, WqT, WkT, WvT, nullptr, nullptr, bv,
        Qb, Kb, Vb, DK, HID, 0);

    // 3) a_raw via gathered prefix K-sums
    gather_attn<<<NROWS, 64, 0, stream>>>(Qb, Kb, sp, a_raw);
    // 4) per-selector max + zero P/Z accumulators
    reduce_max_k<<<3, 1024, 0, stream>>>(a_raw, mx, P, Z);
    // 5) pooled weighted sums
    pool_kernel<<<dim3(NROWS / RPB, 3, 1), 256, 0, stream>>>(a_raw, mx, Vb, P, Z);
    // 6) epilogue
    final_kernel<<<1, 256, 0, stream>>>(P, Z, Wout, bout, out);
}